// Round 7
// baseline (168.831 us; speedup 1.0000x reference)
//
#include <hip/hip_runtime.h>
#include <math.h>

#define NPB   512      // nodes per bucket (N=102400 = 200*512 exactly)
#define NPBL  9
#define MAXR  256      // max buckets
#define TILE  2048     // edges per k_p1 block
#define RPT   8        // records per thread in k_p1
#define GCS   16       // gcur stride in u32 (64B line padding)
#define EPARTS 256     // easum partial count
#define SLICES 4       // k_p2 slices per bucket

static __device__ __forceinline__ float lrelu(float x) { return x > 0.0f ? x : 0.2f * x; }

// consts layout (floats):
// [0] sum_ea, [1] c_edge, [2..6] va, [7..11] vd, [16..143] bc, [144..783] Wc[5][128]

// ---- stage 1: grid-stride partial sums of edge_attr ----
__global__ void k_easum_part(const float* __restrict__ ea, float* __restrict__ part, int n) {
    __shared__ float s[256];
    int t = threadIdx.x;
    int n4 = n >> 2;
    const float4* ea4 = (const float4*)ea;
    float acc = 0.f;
    for (int i = blockIdx.x * 256 + t; i < n4; i += EPARTS * 256) {
        float4 v = ea4[i];
        acc += v.x + v.y + v.z + v.w;
    }
    if (blockIdx.x == 0 && t < (n & 3)) acc += ea[n4 * 4 + t];
    s[t] = acc;
    __syncthreads();
    for (int o = 128; o > 0; o >>= 1) {
        if (t < o) s[t] += s[t + o];
        __syncthreads();
    }
    if (t == 0) part[blockIdx.x] = s[0];
}

// ---- setup: fold weights + finalize easum ----
__global__ void k_setup(const float* __restrict__ W_gat, const float* __restrict__ att_src,
                        const float* __restrict__ att_dst, const float* __restrict__ W_edge,
                        const float* __restrict__ att_edge, const float* __restrict__ b_gat,
                        const float* __restrict__ W_fc1, const float* __restrict__ b_fc1,
                        const float* __restrict__ part, float* __restrict__ consts) {
    __shared__ float s[128];
    int t = threadIdx.x;  // 128 threads
    s[t] = part[t] + part[t + 128];
    __syncthreads();
    for (int o = 64; o > 0; o >>= 1) {
        if (t < o) s[t] += s[t + o];
        __syncthreads();
    }
    if (t == 0) consts[0] = s[0];
    if (t == 0) {
        float c = 0.f;
        for (int k = 0; k < 64; k++) c += W_edge[k] * att_edge[k];
        consts[1] = c;
    }
    if (t < 5) {
        float a = 0.f, b = 0.f;
        for (int c = 0; c < 64; c++) {
            float w = W_gat[t * 64 + c];
            a += w * att_src[c];
            b += w * att_dst[c];
        }
        consts[2 + t] = a;
        consts[7 + t] = b;
    }
    float bcv = b_fc1[t];
    for (int c = 0; c < 64; c++) bcv += b_gat[c] * W_fc1[c * 128 + t];
    consts[16 + t] = bcv;
    for (int k = 0; k < 5; k++) {
        float w = 0.f;
        for (int c = 0; c < 64; c++) w += W_gat[k * 64 + c] * W_fc1[c * 128 + t];
        consts[144 + k * 128 + t] = w;
    }
}

// per-node: xs8 = {x0..x4, a_s, 0, 0} (32B struct, float4-stored), a_d separate; fused bstart
__global__ void k_nodes(const float* __restrict__ x, const float* __restrict__ consts,
                        float* __restrict__ xs8, float* __restrict__ a_d,
                        const int* __restrict__ pb, int* __restrict__ bstart, int n, int B) {
    int i = blockIdx.x * blockDim.x + threadIdx.x;
    if (i >= n) return;
    const float* xi = x + (size_t)i * 5;
    float x0 = xi[0], x1 = xi[1], x2 = xi[2], x3 = xi[3], x4 = xi[4];
    float as = x0 * consts[2] + x1 * consts[3] + x2 * consts[4] + x3 * consts[5] + x4 * consts[6];
    float ad = x0 * consts[7] + x1 * consts[8] + x2 * consts[9] + x3 * consts[10] + x4 * consts[11];
    float4* o = (float4*)(xs8 + (size_t)i * 8);
    o[0] = make_float4(x0, x1, x2, x3);
    o[1] = make_float4(x4, as, 0.f, 0.f);
    a_d[i] = ad;
    int cur = pb[i];
    int prev = (i == 0) ? -1 : pb[i - 1];
    for (int b = prev + 1; b <= cur; b++) bstart[b] = i;
    if (i == n - 1)
        for (int b = cur + 1; b <= B; b++) bstart[b] = n;
}

// ---- phase 1: bin edges by dst bucket; LDS counting sort -> coalesced slab flush ----
// record: {u32 (src<<9)|dstLocal, f32 c_edge*ea[e]}
__global__ void k_p1(const int* __restrict__ src, const int* __restrict__ dst,
                     const float* __restrict__ ea, const float* __restrict__ consts,
                     uint2* __restrict__ slab, unsigned* __restrict__ gcur,
                     int E, int R, int CAP) {
    __shared__ unsigned hist[MAXR], lbase[MAXR], gbase[MAXR], scan[256];
    __shared__ uint2 staged[TILE];
    __shared__ unsigned char bof[TILE];
    int t = threadIdx.x;  // 256
    int e0 = blockIdx.x * TILE;
    int n = E - e0; if (n > TILE) n = TILE;
    for (int i = t; i < MAXR; i += 256) hist[i] = 0;
    __syncthreads();
    unsigned key[RPT]; float val[RPT]; unsigned brk[RPT];
    float ce = consts[1];
#pragma unroll
    for (int k = 0; k < RPT; k++) {
        int idx = t + k * 256;
        brk[k] = 0xFFFFFFFFu;
        if (idx < n) {
            int e = e0 + idx;
            int d = dst[e];
            unsigned b = (unsigned)d >> NPBL;
            key[k] = ((unsigned)src[e] << NPBL) | ((unsigned)d & (NPB - 1));
            val[k] = ce * ea[e];
            unsigned r = atomicAdd(&hist[b], 1u);
            brk[k] = (b << 12) | r;
        }
    }
    __syncthreads();
    unsigned v = (t < R) ? hist[t] : 0;
    if (t < R) gbase[t] = atomicAdd(&gcur[t * GCS], v);
    scan[t] = v;
    __syncthreads();
    for (int off = 1; off < 256; off <<= 1) {
        unsigned add = (t >= off) ? scan[t - off] : 0;
        __syncthreads();
        scan[t] += add;
        __syncthreads();
    }
    if (t < R) lbase[t] = scan[t] - v;
    __syncthreads();
#pragma unroll
    for (int k = 0; k < RPT; k++) {
        if (brk[k] != 0xFFFFFFFFu) {
            unsigned b = brk[k] >> 12, r = brk[k] & 4095u;
            unsigned pos = lbase[b] + r;
            staged[pos] = make_uint2(key[k], __float_as_uint(val[k]));
            bof[pos] = (unsigned char)b;
        }
    }
    __syncthreads();
    for (int i = t; i < n; i += 256) {
        unsigned b = bof[i];
        unsigned slot = gbase[b] + (unsigned)i - lbase[b];
        if (slot < (unsigned)CAP) slab[(size_t)b * CAP + slot] = staged[i];
    }
}

// ---- phase 2: per (slice s, bucket r): LDS aggregation with NATIVE ds_add_f32 ----
// partials layout (SoA): [r][s][6][NPB]
__global__ void k_p2(const uint2* __restrict__ slab, const unsigned* __restrict__ gcur,
                     const float* __restrict__ xs8, const float* __restrict__ a_d,
                     float* __restrict__ partials, int S, int CAP, int N) {
    __shared__ float acc[NPB * 6];   // 12.3 KB
    __shared__ float adl[NPB];       // 2 KB
    int t = threadIdx.x;  // 256
    int s = blockIdx.x, r = blockIdx.y;
    for (int i = t; i < NPB; i += 256) {
        int node = r * NPB + i;
        adl[i] = (node < N) ? a_d[node] : 0.f;
    }
    for (int i = t; i < NPB * 6; i += 256) acc[i] = 0.f;
    __syncthreads();
    unsigned cnt = gcur[r * GCS]; if (cnt > (unsigned)CAP) cnt = CAP;
    unsigned L = (cnt + (unsigned)S - 1) / (unsigned)S;
    unsigned i0 = (unsigned)s * L, i1 = i0 + L; if (i1 > cnt) i1 = cnt;
    const uint2* sl = slab + (size_t)r * CAP;
    unsigned i = i0 + t;
    for (; i + 768 < i1; i += 1024) {
        uint2 r0 = sl[i], r1 = sl[i + 256], r2 = sl[i + 512], r3 = sl[i + 768];
        const float4* p0 = (const float4*)(xs8 + (size_t)(r0.x >> NPBL) * 8);
        const float4* p1 = (const float4*)(xs8 + (size_t)(r1.x >> NPBL) * 8);
        const float4* p2 = (const float4*)(xs8 + (size_t)(r2.x >> NPBL) * 8);
        const float4* p3 = (const float4*)(xs8 + (size_t)(r3.x >> NPBL) * 8);
        float4 lo0 = p0[0], hi0 = p0[1];
        float4 lo1 = p1[0], hi1 = p1[1];
        float4 lo2 = p2[0], hi2 = p2[1];
        float4 lo3 = p3[0], hi3 = p3[1];
#define DO_REC(rr, lo, hi) { \
        unsigned dl = rr.x & (NPB - 1); \
        float ex = __expf(lrelu(hi.y + adl[dl] + __uint_as_float(rr.y))); \
        float* a = acc + dl * 6; \
        unsafeAtomicAdd(a + 0, ex * lo.x); \
        unsafeAtomicAdd(a + 1, ex * lo.y); \
        unsafeAtomicAdd(a + 2, ex * lo.z); \
        unsafeAtomicAdd(a + 3, ex * lo.w); \
        unsafeAtomicAdd(a + 4, ex * hi.x); \
        unsafeAtomicAdd(a + 5, ex); }
        DO_REC(r0, lo0, hi0)
        DO_REC(r1, lo1, hi1)
        DO_REC(r2, lo2, hi2)
        DO_REC(r3, lo3, hi3)
    }
    for (; i < i1; i += 256) {
        uint2 r0 = sl[i];
        const float4* p0 = (const float4*)(xs8 + (size_t)(r0.x >> NPBL) * 8);
        float4 lo0 = p0[0], hi0 = p0[1];
        DO_REC(r0, lo0, hi0)
    }
#undef DO_REC
    __syncthreads();
    // SoA transpose writeout: out[comp*NPB + dl] = acc[dl*6 + comp]
    float* out = partials + (size_t)(r * S + s) * (NPB * 6);
    for (int j = t; j < NPB * 6; j += 256) {
        int comp = j >> NPBL, dl = j & (NPB - 1);
        out[j] = acc[dl * 6 + comp];
    }
}

// ---- phase 3: merge S partials + self-loop, normalize -> y SoA [5][N] ----
__global__ void k_p3(const float* __restrict__ partials, const float* __restrict__ xs8,
                     const float* __restrict__ a_d, const float* __restrict__ consts,
                     float* __restrict__ y, int N, int S, float inv_E) {
    int i = blockIdx.x * blockDim.x + threadIdx.x;
    if (i >= N) return;
    int r = i >> NPBL, dl = i & (NPB - 1);
    float y0 = 0, y1 = 0, y2 = 0, y3 = 0, y4 = 0, ss = 0;
    const float* p = partials + (size_t)r * S * (NPB * 6) + dl;
    for (int s = 0; s < S; s++) {
        const float* q = p + (size_t)s * (NPB * 6);
        y0 += q[0 * NPB]; y1 += q[1 * NPB]; y2 += q[2 * NPB];
        y3 += q[3 * NPB]; y4 += q[4 * NPB]; ss += q[5 * NPB];
    }
    const float4* xp = (const float4*)(xs8 + (size_t)i * 8);
    float4 lo = xp[0], hi = xp[1];
    float mean_ea = consts[0] * inv_E;
    float aself = lrelu(hi.y + a_d[i] + consts[1] * mean_ea);
    float exs = __expf(aself);
    float inv = 1.f / (ss + exs + 1e-16f);
    y[0 * (size_t)N + i] = (y0 + exs * lo.x) * inv;
    y[1 * (size_t)N + i] = (y1 + exs * lo.y) * inv;
    y[2 * (size_t)N + i] = (y2 + exs * lo.z) * inv;
    y[3 * (size_t)N + i] = (y3 + exs * lo.w) * inv;
    y[4 * (size_t)N + i] = (y4 + exs * hi.x) * inv;
}

// ---- pool: 2 blocks per batch, register accumulate, direct store (no atomics) ----
__global__ void k_pool(const float* __restrict__ y, const float* __restrict__ consts,
                       const int* __restrict__ bstart, float* __restrict__ g2, int B, int N) {
    int l = threadIdx.x;  // 128 threads
    int b = blockIdx.x >> 1, half = blockIdx.x & 1;
    int st = bstart[b], en = bstart[b + 1];
    int len = en - st;
    int h0 = (len + 1) >> 1;
    int i0 = half ? st + h0 : st;
    int i1 = half ? en : st + h0;
    float w0 = consts[144 + l], w1 = consts[272 + l], w2 = consts[400 + l],
          w3 = consts[528 + l], w4 = consts[656 + l];
    float bc = consts[16 + l];
    const float* y0 = y;
    const float* y1p = y + (size_t)N;
    const float* y2p = y + 2 * (size_t)N;
    const float* y3p = y + 3 * (size_t)N;
    const float* y4p = y + 4 * (size_t)N;
    float accum = 0.f;
    for (int i = i0; i < i1; ++i) {
        float h = bc + y0[i] * w0 + y1p[i] * w1 + y2p[i] * w2 + y3p[i] * w3 + y4p[i] * w4;
        accum += fmaxf(h, 0.f);
    }
    g2[((size_t)half * B + b) * 128 + l] = accum;
}

// ---- head MLP: one block per batch row ----
__global__ void k_head(const float* __restrict__ g2, const int* __restrict__ bstart,
                       const float* __restrict__ agent_state, const float* __restrict__ W_fc2,
                       const float* __restrict__ b_fc2, const float* __restrict__ W_v1,
                       const float* __restrict__ b_v1, const float* __restrict__ W_v2,
                       const float* __restrict__ b_v2, const float* __restrict__ W_a1,
                       const float* __restrict__ b_a1, const float* __restrict__ W_a2,
                       const float* __restrict__ b_a2, float* __restrict__ out, int A, int B) {
    __shared__ float z[192];
    __shared__ float v1s[128], a1s[128], red[128];
    __shared__ float advs[8];
    int b = blockIdx.x, t = threadIdx.x;  // 128 threads
    float cnt = (float)(bstart[b + 1] - bstart[b]);
    cnt = cnt < 1.f ? 1.f : cnt;
    z[t] = (g2[(size_t)b * 128 + t] + g2[((size_t)B + b) * 128 + t]) / cnt;
    if (t < 64) {
        float a = b_fc2[t];
        const float* as_ = agent_state + b * 34;
        for (int k = 0; k < 34; k++) a += as_[k] * W_fc2[k * 64 + t];
        z[128 + t] = fmaxf(a, 0.f);
    }
    __syncthreads();
    float v = b_v1[t], a = b_a1[t];
    for (int j = 0; j < 192; j++) {
        float zj = z[j];
        v += zj * W_v1[j * 128 + t];
        a += zj * W_a1[j * 128 + t];
    }
    v1s[t] = fmaxf(v, 0.f);
    a1s[t] = fmaxf(a, 0.f);
    __syncthreads();
    red[t] = v1s[t] * W_v2[t];
    __syncthreads();
    for (int o = 64; o > 0; o >>= 1) {
        if (t < o) red[t] += red[t + o];
        __syncthreads();
    }
    float value = red[0] + b_v2[0];
    if (t < A) {
        float ad = b_a2[t];
        for (int j = 0; j < 128; j++) ad += a1s[j] * W_a2[j * A + t];
        advs[t] = ad;
    }
    __syncthreads();
    if (t == 0) {
        float m = 0.f;
        for (int j = 0; j < A; j++) m += advs[j];
        m *= (1.f / (float)A);
        for (int j = 0; j < A; j++) out[b * A + j] = value + advs[j] - m;
    }
}

extern "C" void kernel_launch(void* const* d_in, const int* in_sizes, int n_in,
                              void* d_out, int out_size, void* d_ws, size_t ws_size,
                              hipStream_t stream) {
    const float* x        = (const float*)d_in[0];
    const int* edge_index = (const int*)d_in[1];
    const float* ea       = (const float*)d_in[2];
    const float* agent    = (const float*)d_in[3];
    const int* pool_batch = (const int*)d_in[4];
    const float* W_gat    = (const float*)d_in[5];
    const float* att_src  = (const float*)d_in[6];
    const float* att_dst  = (const float*)d_in[7];
    const float* W_edge   = (const float*)d_in[8];
    const float* att_edge = (const float*)d_in[9];
    const float* b_gat    = (const float*)d_in[10];
    const float* W_fc1    = (const float*)d_in[11];
    const float* b_fc1    = (const float*)d_in[12];
    const float* W_fc2    = (const float*)d_in[13];
    const float* b_fc2    = (const float*)d_in[14];
    const float* W_v1     = (const float*)d_in[15];
    const float* b_v1     = (const float*)d_in[16];
    const float* W_v2     = (const float*)d_in[17];
    const float* b_v2     = (const float*)d_in[18];
    const float* W_a1     = (const float*)d_in[19];
    const float* b_a1     = (const float*)d_in[20];
    const float* W_a2     = (const float*)d_in[21];
    const float* b_a2     = (const float*)d_in[22];

    const int N = in_sizes[0] / 5;
    const int E = in_sizes[2];
    const int B = in_sizes[3] / 34;
    const int A = out_size / B;
    const float inv_E = 1.0f / (float)E;

    const int* src = edge_index;
    const int* dst = edge_index + E;

    const int R = (N + NPB - 1) / NPB;            // 200 buckets
    int capBase = (E + R - 1) / R;                // ~8192
    const int CAP = capBase + capBase / 16 + 256;

    // ---- ws layout ----
    char* ws = (char*)d_ws;
    size_t off = 0;
    auto take = [&](size_t bytes) {
        size_t o = off;
        off = (off + bytes + 255) & ~(size_t)255;
        return o;
    };
    size_t o_consts = take(4096);                       // zeroed
    size_t o_gcur   = take((size_t)MAXR * GCS * 4);     // zeroed (64B-padded counters)
    size_t zero_bytes = off;
    size_t o_epart  = take((size_t)EPARTS * 4);
    size_t o_xs8    = take((size_t)N * 8 * 4);
    size_t o_ad     = take((size_t)N * 4);
    size_t o_y      = take((size_t)N * 5 * 4);
    size_t o_bstart = take((size_t)(B + 1) * 4);
    size_t o_g2     = take((size_t)2 * B * 128 * 4);
    size_t o_slab   = take((size_t)R * CAP * 8);
    size_t o_part   = off;
    size_t perS = (size_t)R * NPB * 6 * 4;
    int S = SLICES;
    while (S > 1 && o_part + (size_t)S * perS > ws_size) S--;

    float* consts   = (float*)(ws + o_consts);
    unsigned* gcur  = (unsigned*)(ws + o_gcur);
    float* epart    = (float*)(ws + o_epart);
    float* xs8      = (float*)(ws + o_xs8);
    float* a_d      = (float*)(ws + o_ad);
    float* y        = (float*)(ws + o_y);
    int* bstart     = (int*)(ws + o_bstart);
    float* g2       = (float*)(ws + o_g2);
    uint2* slab     = (uint2*)(ws + o_slab);
    float* partials = (float*)(ws + o_part);

    hipMemsetAsync(d_ws, 0, zero_bytes, stream);

    k_easum_part<<<EPARTS, 256, 0, stream>>>(ea, epart, E);
    k_setup<<<1, 128, 0, stream>>>(W_gat, att_src, att_dst, W_edge, att_edge, b_gat,
                                   W_fc1, b_fc1, epart, consts);

    int nbl = (N + 255) / 256;
    k_nodes<<<nbl, 256, 0, stream>>>(x, consts, xs8, a_d, pool_batch, bstart, N, B);
    k_p1<<<(E + TILE - 1) / TILE, 256, 0, stream>>>(src, dst, ea, consts, slab, gcur, E, R, CAP);
    dim3 g2grid(S, R);
    k_p2<<<g2grid, 256, 0, stream>>>(slab, gcur, xs8, a_d, partials, S, CAP, N);
    k_p3<<<nbl, 256, 0, stream>>>(partials, xs8, a_d, consts, y, N, S, inv_E);
    k_pool<<<2 * B, 128, 0, stream>>>(y, consts, bstart, g2, B, N);
    k_head<<<B, 128, 0, stream>>>(g2, bstart, agent, W_fc2, b_fc2, W_v1, b_v1, W_v2, b_v2,
                                  W_a1, b_a1, W_a2, b_a2, (float*)d_out, A, B);
}

// Round 9
// 157.251 us; speedup vs baseline: 1.0736x; 1.0736x over previous
//
#include <hip/hip_runtime.h>
#include <math.h>

#define NPB   512      // nodes per bucket (N=102400 = 200*512 exactly)
#define NPBL  9
#define MAXR  256      // max buckets
#define TILE  2048     // edges per k_p1 block
#define RPT   8        // records per thread in k_p1
#define GCS   16       // gcur stride in u32 (64B line padding)
#define EPARTS 256     // easum partial count
#define SLICES 8       // k_p2 slices per bucket

typedef float f32x4 __attribute__((ext_vector_type(4)));

static __device__ __forceinline__ float lrelu(float x) { return x > 0.0f ? x : 0.2f * x; }

// consts layout (floats):
// [0] sum_ea, [1] c_edge, [2..6] va, [7..11] vd, [16..143] bc, [144..783] Wc[5][128]

// ---- stage 1: grid-stride partial sums of edge_attr ----
__global__ void k_easum_part(const float* __restrict__ ea, float* __restrict__ part, int n) {
    __shared__ float s[256];
    int t = threadIdx.x;
    int n4 = n >> 2;
    const float4* ea4 = (const float4*)ea;
    float acc = 0.f;
    for (int i = blockIdx.x * 256 + t; i < n4; i += EPARTS * 256) {
        float4 v = ea4[i];
        acc += v.x + v.y + v.z + v.w;
    }
    if (blockIdx.x == 0 && t < (n & 3)) acc += ea[n4 * 4 + t];
    s[t] = acc;
    __syncthreads();
    for (int o = 128; o > 0; o >>= 1) {
        if (t < o) s[t] += s[t + o];
        __syncthreads();
    }
    if (t == 0) part[blockIdx.x] = s[0];
}

// ---- setup: fold weights + finalize easum ----
__global__ void k_setup(const float* __restrict__ W_gat, const float* __restrict__ att_src,
                        const float* __restrict__ att_dst, const float* __restrict__ W_edge,
                        const float* __restrict__ att_edge, const float* __restrict__ b_gat,
                        const float* __restrict__ W_fc1, const float* __restrict__ b_fc1,
                        const float* __restrict__ part, float* __restrict__ consts) {
    __shared__ float s[128];
    int t = threadIdx.x;  // 128 threads
    s[t] = part[t] + part[t + 128];
    __syncthreads();
    for (int o = 64; o > 0; o >>= 1) {
        if (t < o) s[t] += s[t + o];
        __syncthreads();
    }
    if (t == 0) consts[0] = s[0];
    if (t == 0) {
        float c = 0.f;
        for (int k = 0; k < 64; k++) c += W_edge[k] * att_edge[k];
        consts[1] = c;
    }
    if (t < 5) {
        float a = 0.f, b = 0.f;
        for (int c = 0; c < 64; c++) {
            float w = W_gat[t * 64 + c];
            a += w * att_src[c];
            b += w * att_dst[c];
        }
        consts[2 + t] = a;
        consts[7 + t] = b;
    }
    float bcv = b_fc1[t];
    for (int c = 0; c < 64; c++) bcv += b_gat[c] * W_fc1[c * 128 + t];
    consts[16 + t] = bcv;
    for (int k = 0; k < 5; k++) {
        float w = 0.f;
        for (int c = 0; c < 64; c++) w += W_gat[k * 64 + c] * W_fc1[c * 128 + t];
        consts[144 + k * 128 + t] = w;
    }
}

// ---- merged: blocks [0,nbl) do per-node prep; blocks [nbl,nbl+ebl) do edge binning ----
__global__ void k_np1(const float* __restrict__ x, const float* __restrict__ consts,
                      float* __restrict__ xs8, float* __restrict__ a_d,
                      const int* __restrict__ pb, int* __restrict__ bstart,
                      const int* __restrict__ src, const int* __restrict__ dst,
                      const float* __restrict__ ea,
                      uint2* __restrict__ slab, unsigned* __restrict__ gcur,
                      int N, int B, int E, int R, int CAP, int nbl) {
    if ((int)blockIdx.x < nbl) {
        int i = blockIdx.x * blockDim.x + threadIdx.x;
        if (i >= N) return;
        const float* xi = x + (size_t)i * 5;
        float x0 = xi[0], x1 = xi[1], x2 = xi[2], x3 = xi[3], x4 = xi[4];
        float as = x0 * consts[2] + x1 * consts[3] + x2 * consts[4] + x3 * consts[5] + x4 * consts[6];
        float ad = x0 * consts[7] + x1 * consts[8] + x2 * consts[9] + x3 * consts[10] + x4 * consts[11];
        float4* o = (float4*)(xs8 + (size_t)i * 8);
        o[0] = make_float4(x0, x1, x2, x3);
        o[1] = make_float4(x4, as, 0.f, 0.f);
        a_d[i] = ad;
        int cur = pb[i];
        int prev = (i == 0) ? -1 : pb[i - 1];
        for (int b = prev + 1; b <= cur; b++) bstart[b] = i;
        if (i == N - 1)
            for (int b = cur + 1; b <= B; b++) bstart[b] = N;
        return;
    }
    __shared__ unsigned hist[MAXR], lbase[MAXR], gbase[MAXR], scan[256];
    __shared__ uint2 staged[TILE];
    __shared__ unsigned char bof[TILE];
    int t = threadIdx.x;  // 256
    int e0 = ((int)blockIdx.x - nbl) * TILE;
    int n = E - e0; if (n > TILE) n = TILE;
    for (int i = t; i < MAXR; i += 256) hist[i] = 0;
    __syncthreads();
    unsigned key[RPT]; float val[RPT]; unsigned brk[RPT];
    float ce = consts[1];
#pragma unroll
    for (int k = 0; k < RPT; k++) {
        int idx = t + k * 256;
        brk[k] = 0xFFFFFFFFu;
        if (idx < n) {
            int e = e0 + idx;
            int d = dst[e];
            unsigned b = (unsigned)d >> NPBL;
            key[k] = ((unsigned)src[e] << NPBL) | ((unsigned)d & (NPB - 1));
            val[k] = ce * ea[e];
            unsigned r = atomicAdd(&hist[b], 1u);
            brk[k] = (b << 12) | r;
        }
    }
    __syncthreads();
    unsigned v = (t < R) ? hist[t] : 0;
    if (t < R) gbase[t] = atomicAdd(&gcur[t * GCS], v);
    scan[t] = v;
    __syncthreads();
    for (int off = 1; off < 256; off <<= 1) {
        unsigned add = (t >= off) ? scan[t - off] : 0;
        __syncthreads();
        scan[t] += add;
        __syncthreads();
    }
    if (t < R) lbase[t] = scan[t] - v;
    __syncthreads();
#pragma unroll
    for (int k = 0; k < RPT; k++) {
        if (brk[k] != 0xFFFFFFFFu) {
            unsigned b = brk[k] >> 12, r = brk[k] & 4095u;
            unsigned pos = lbase[b] + r;
            staged[pos] = make_uint2(key[k], __float_as_uint(val[k]));
            bof[pos] = (unsigned char)b;
        }
    }
    __syncthreads();
    for (int i = t; i < n; i += 256) {
        unsigned b = bof[i];
        unsigned slot = gbase[b] + (unsigned)i - lbase[b];
        if (slot < (unsigned)CAP) slab[(size_t)b * CAP + slot] = staged[i];
    }
}

// ---- phase 2: per (slice s, bucket r): LDS aggregation; NT vector gathers, native ds_add ----
// partials layout (SoA): [r][s][6][NPB]
__global__ void k_p2(const uint2* __restrict__ slab, const unsigned* __restrict__ gcur,
                     const float* __restrict__ xs8, const float* __restrict__ a_d,
                     float* __restrict__ partials, int S, int CAP, int N) {
    __shared__ float acc[NPB * 6];   // 12.3 KB
    __shared__ float adl[NPB];       // 2 KB
    int t = threadIdx.x;  // 256
    int s = blockIdx.x, r = blockIdx.y;
    for (int i = t; i < NPB; i += 256) {
        int node = r * NPB + i;
        adl[i] = (node < N) ? a_d[node] : 0.f;
    }
    for (int i = t; i < NPB * 6; i += 256) acc[i] = 0.f;
    __syncthreads();
    unsigned cnt = gcur[r * GCS]; if (cnt > (unsigned)CAP) cnt = CAP;
    unsigned L = (cnt + (unsigned)S - 1) / (unsigned)S;
    unsigned i0 = (unsigned)s * L, i1 = i0 + L; if (i1 > cnt) i1 = cnt;
    const uint2* sl = slab + (size_t)r * CAP;
    for (unsigned i = i0 + t; i < i1; i += 256) {
        uint2 rec = sl[i];
        const f32x4* xp = (const f32x4*)(xs8 + (size_t)(rec.x >> NPBL) * 8);
        f32x4 lo = __builtin_nontemporal_load(xp);
        f32x4 hi = __builtin_nontemporal_load(xp + 1);
        unsigned dl = rec.x & (NPB - 1);
        float ex = __expf(lrelu(hi.y + adl[dl] + __uint_as_float(rec.y)));
        float* a = acc + dl * 6;
        unsafeAtomicAdd(a + 0, ex * lo.x);
        unsafeAtomicAdd(a + 1, ex * lo.y);
        unsafeAtomicAdd(a + 2, ex * lo.z);
        unsafeAtomicAdd(a + 3, ex * lo.w);
        unsafeAtomicAdd(a + 4, ex * hi.x);
        unsafeAtomicAdd(a + 5, ex);
    }
    __syncthreads();
    // SoA transpose writeout: out[comp*NPB + dl] = acc[dl*6 + comp]
    float* out = partials + (size_t)(r * S + s) * (NPB * 6);
    for (int j = t; j < NPB * 6; j += 256) {
        int comp = j >> NPBL, dl = j & (NPB - 1);
        out[j] = acc[dl * 6 + comp];
    }
}

// ---- phase 3: merge S partials + self-loop, normalize -> y SoA [5][N] ----
__global__ void k_p3(const float* __restrict__ partials, const float* __restrict__ xs8,
                     const float* __restrict__ a_d, const float* __restrict__ consts,
                     float* __restrict__ y, int N, int S, float inv_E) {
    int i = blockIdx.x * blockDim.x + threadIdx.x;
    if (i >= N) return;
    int r = i >> NPBL, dl = i & (NPB - 1);
    float y0 = 0, y1 = 0, y2 = 0, y3 = 0, y4 = 0, ss = 0;
    const float* p = partials + (size_t)r * S * (NPB * 6) + dl;
    for (int s = 0; s < S; s++) {
        const float* q = p + (size_t)s * (NPB * 6);
        y0 += q[0 * NPB]; y1 += q[1 * NPB]; y2 += q[2 * NPB];
        y3 += q[3 * NPB]; y4 += q[4 * NPB]; ss += q[5 * NPB];
    }
    const float4* xp = (const float4*)(xs8 + (size_t)i * 8);
    float4 lo = xp[0], hi = xp[1];
    float mean_ea = consts[0] * inv_E;
    float aself = lrelu(hi.y + a_d[i] + consts[1] * mean_ea);
    float exs = __expf(aself);
    float inv = 1.f / (ss + exs + 1e-16f);
    y[0 * (size_t)N + i] = (y0 + exs * lo.x) * inv;
    y[1 * (size_t)N + i] = (y1 + exs * lo.y) * inv;
    y[2 * (size_t)N + i] = (y2 + exs * lo.z) * inv;
    y[3 * (size_t)N + i] = (y3 + exs * lo.w) * inv;
    y[4 * (size_t)N + i] = (y4 + exs * hi.x) * inv;
}

// ---- pool: 4 quarter-blocks per batch, unroll-4, 4 indep chains, direct store ----
__global__ void k_pool(const float* __restrict__ y, const float* __restrict__ consts,
                       const int* __restrict__ bstart, float* __restrict__ g4, int B, int N) {
    int l = threadIdx.x;  // 128 threads
    int b = blockIdx.x >> 2, q = blockIdx.x & 3;
    int st = bstart[b], en = bstart[b + 1];
    int len = en - st;
    int qlen = (len + 3) >> 2;
    int i0 = st + q * qlen;
    int i1 = i0 + qlen;
    if (i0 > en) i0 = en;
    if (i1 > en) i1 = en;
    float w0 = consts[144 + l], w1 = consts[272 + l], w2 = consts[400 + l],
          w3 = consts[528 + l], w4 = consts[656 + l];
    float bc = consts[16 + l];
    const float* y0 = y;
    const float* y1p = y + (size_t)N;
    const float* y2p = y + 2 * (size_t)N;
    const float* y3p = y + 3 * (size_t)N;
    const float* y4p = y + 4 * (size_t)N;
    float a0 = 0.f, a1 = 0.f, a2 = 0.f, a3 = 0.f;
    int i = i0;
    for (; i + 3 < i1; i += 4) {
        float h0 = bc + y0[i] * w0 + y1p[i] * w1 + y2p[i] * w2 + y3p[i] * w3 + y4p[i] * w4;
        float h1 = bc + y0[i+1] * w0 + y1p[i+1] * w1 + y2p[i+1] * w2 + y3p[i+1] * w3 + y4p[i+1] * w4;
        float h2 = bc + y0[i+2] * w0 + y1p[i+2] * w1 + y2p[i+2] * w2 + y3p[i+2] * w3 + y4p[i+2] * w4;
        float h3 = bc + y0[i+3] * w0 + y1p[i+3] * w1 + y2p[i+3] * w2 + y3p[i+3] * w3 + y4p[i+3] * w4;
        a0 += fmaxf(h0, 0.f);
        a1 += fmaxf(h1, 0.f);
        a2 += fmaxf(h2, 0.f);
        a3 += fmaxf(h3, 0.f);
    }
    for (; i < i1; ++i) {
        float h = bc + y0[i] * w0 + y1p[i] * w1 + y2p[i] * w2 + y3p[i] * w3 + y4p[i] * w4;
        a0 += fmaxf(h, 0.f);
    }
    g4[((size_t)q * B + b) * 128 + l] = (a0 + a1) + (a2 + a3);
}

// ---- head MLP: one block per batch row ----
__global__ void k_head(const float* __restrict__ g4, const int* __restrict__ bstart,
                       const float* __restrict__ agent_state, const float* __restrict__ W_fc2,
                       const float* __restrict__ b_fc2, const float* __restrict__ W_v1,
                       const float* __restrict__ b_v1, const float* __restrict__ W_v2,
                       const float* __restrict__ b_v2, const float* __restrict__ W_a1,
                       const float* __restrict__ b_a1, const float* __restrict__ W_a2,
                       const float* __restrict__ b_a2, float* __restrict__ out, int A, int B) {
    __shared__ float z[192];
    __shared__ float v1s[128], a1s[128], red[128];
    __shared__ float advs[8];
    int b = blockIdx.x, t = threadIdx.x;  // 128 threads
    float cnt = (float)(bstart[b + 1] - bstart[b]);
    cnt = cnt < 1.f ? 1.f : cnt;
    z[t] = (g4[(size_t)b * 128 + t] + g4[((size_t)B + b) * 128 + t]
          + g4[(2 * (size_t)B + b) * 128 + t] + g4[(3 * (size_t)B + b) * 128 + t]) / cnt;
    if (t < 64) {
        float a = b_fc2[t];
        const float* as_ = agent_state + b * 34;
        for (int k = 0; k < 34; k++) a += as_[k] * W_fc2[k * 64 + t];
        z[128 + t] = fmaxf(a, 0.f);
    }
    __syncthreads();
    float v = b_v1[t], a = b_a1[t];
#pragma unroll 4
    for (int j = 0; j < 192; j++) {
        float zj = z[j];
        v += zj * W_v1[j * 128 + t];
        a += zj * W_a1[j * 128 + t];
    }
    v1s[t] = fmaxf(v, 0.f);
    a1s[t] = fmaxf(a, 0.f);
    __syncthreads();
    red[t] = v1s[t] * W_v2[t];
    __syncthreads();
    for (int o = 64; o > 0; o >>= 1) {
        if (t < o) red[t] += red[t + o];
        __syncthreads();
    }
    float value = red[0] + b_v2[0];
    if (t < A) {
        float ad = b_a2[t];
        for (int j = 0; j < 128; j++) ad += a1s[j] * W_a2[j * A + t];
        advs[t] = ad;
    }
    __syncthreads();
    if (t == 0) {
        float m = 0.f;
        for (int j = 0; j < A; j++) m += advs[j];
        m *= (1.f / (float)A);
        for (int j = 0; j < A; j++) out[b * A + j] = value + advs[j] - m;
    }
}

extern "C" void kernel_launch(void* const* d_in, const int* in_sizes, int n_in,
                              void* d_out, int out_size, void* d_ws, size_t ws_size,
                              hipStream_t stream) {
    const float* x        = (const float*)d_in[0];
    const int* edge_index = (const int*)d_in[1];
    const float* ea       = (const float*)d_in[2];
    const float* agent    = (const float*)d_in[3];
    const int* pool_batch = (const int*)d_in[4];
    const float* W_gat    = (const float*)d_in[5];
    const float* att_src  = (const float*)d_in[6];
    const float* att_dst  = (const float*)d_in[7];
    const float* W_edge   = (const float*)d_in[8];
    const float* att_edge = (const float*)d_in[9];
    const float* b_gat    = (const float*)d_in[10];
    const float* W_fc1    = (const float*)d_in[11];
    const float* b_fc1    = (const float*)d_in[12];
    const float* W_fc2    = (const float*)d_in[13];
    const float* b_fc2    = (const float*)d_in[14];
    const float* W_v1     = (const float*)d_in[15];
    const float* b_v1     = (const float*)d_in[16];
    const float* W_v2     = (const float*)d_in[17];
    const float* b_v2     = (const float*)d_in[18];
    const float* W_a1     = (const float*)d_in[19];
    const float* b_a1     = (const float*)d_in[20];
    const float* W_a2     = (const float*)d_in[21];
    const float* b_a2     = (const float*)d_in[22];

    const int N = in_sizes[0] / 5;
    const int E = in_sizes[2];
    const int B = in_sizes[3] / 34;
    const int A = out_size / B;
    const float inv_E = 1.0f / (float)E;

    const int* src = edge_index;
    const int* dst = edge_index + E;

    const int R = (N + NPB - 1) / NPB;            // 200 buckets
    int capBase = (E + R - 1) / R;                // ~8192
    const int CAP = capBase + capBase / 16 + 256;

    // ---- ws layout ----
    char* ws = (char*)d_ws;
    size_t off = 0;
    auto take = [&](size_t bytes) {
        size_t o = off;
        off = (off + bytes + 255) & ~(size_t)255;
        return o;
    };
    size_t o_consts = take(4096);                       // zeroed
    size_t o_gcur   = take((size_t)MAXR * GCS * 4);     // zeroed (64B-padded counters)
    size_t zero_bytes = off;
    size_t o_epart  = take((size_t)EPARTS * 4);
    size_t o_xs8    = take((size_t)N * 8 * 4);
    size_t o_ad     = take((size_t)N * 4);
    size_t o_y      = take((size_t)N * 5 * 4);
    size_t o_bstart = take((size_t)(B + 1) * 4);
    size_t o_g4     = take((size_t)4 * B * 128 * 4);
    size_t o_slab   = take((size_t)R * CAP * 8);
    size_t o_part   = off;
    size_t perS = (size_t)R * NPB * 6 * 4;
    int S = SLICES;
    while (S > 1 && o_part + (size_t)S * perS > ws_size) S--;

    float* consts   = (float*)(ws + o_consts);
    unsigned* gcur  = (unsigned*)(ws + o_gcur);
    float* epart    = (float*)(ws + o_epart);
    float* xs8      = (float*)(ws + o_xs8);
    float* a_d      = (float*)(ws + o_ad);
    float* y        = (float*)(ws + o_y);
    int* bstart     = (int*)(ws + o_bstart);
    float* g4       = (float*)(ws + o_g4);
    uint2* slab     = (uint2*)(ws + o_slab);
    float* partials = (float*)(ws + o_part);

    (void)hipMemsetAsync(d_ws, 0, zero_bytes, stream);

    k_easum_part<<<EPARTS, 256, 0, stream>>>(ea, epart, E);
    k_setup<<<1, 128, 0, stream>>>(W_gat, att_src, att_dst, W_edge, att_edge, b_gat,
                                   W_fc1, b_fc1, epart, consts);

    int nbl = (N + 255) / 256;
    int ebl = (E + TILE - 1) / TILE;
    k_np1<<<nbl + ebl, 256, 0, stream>>>(x, consts, xs8, a_d, pool_batch, bstart,
                                         src, dst, ea, slab, gcur, N, B, E, R, CAP, nbl);
    dim3 g2grid(S, R);
    k_p2<<<g2grid, 256, 0, stream>>>(slab, gcur, xs8, a_d, partials, S, CAP, N);
    k_p3<<<nbl, 256, 0, stream>>>(partials, xs8, a_d, consts, y, N, S, inv_E);
    k_pool<<<4 * B, 128, 0, stream>>>(y, consts, bstart, g4, B, N);
    k_head<<<B, 128, 0, stream>>>(g4, bstart, agent, W_fc2, b_fc2, W_v1, b_v1, W_v2, b_v2,
                                  W_a1, b_a1, W_a2, b_a2, (float*)d_out, A, B);
}

// Round 10
// 155.647 us; speedup vs baseline: 1.0847x; 1.0103x over previous
//
#include <hip/hip_runtime.h>
#include <hip/hip_fp16.h>
#include <math.h>

#define NPB   512      // nodes per bucket (N=102400 = 200*512 exactly)
#define NPBL  9
#define ASTR  7        // acc stride in floats (gcd(7,32)=1 -> all 32 banks)
#define MAXR  256      // max buckets
#define TILE  2048     // edges per k_p1 block
#define RPT   8        // records per thread in k_p1
#define GCS   16       // gcur stride in u32 (64B line padding)
#define EPARTS 256     // easum partial count
#define SLICES 8       // k_p2 slices per bucket

static __device__ __forceinline__ float lrelu(float x) { return x > 0.0f ? x : 0.2f * x; }

static __device__ __forceinline__ unsigned pk2(float a, float b) {
    __half2 h = __floats2half2_rn(a, b);
    return *reinterpret_cast<unsigned*>(&h);
}
static __device__ __forceinline__ float2 up2(unsigned u) {
    __half2 h = *reinterpret_cast<__half2*>(&u);
    return __half22float2(h);
}

// consts layout (floats):
// [0] sum_ea, [1] c_edge, [2..6] va, [7..11] vd, [16..143] bc, [144..783] Wc[5][128]

// ---- stage 1: grid-stride partial sums of edge_attr ----
__global__ void k_easum_part(const float* __restrict__ ea, float* __restrict__ part, int n) {
    __shared__ float s[256];
    int t = threadIdx.x;
    int n4 = n >> 2;
    const float4* ea4 = (const float4*)ea;
    float acc = 0.f;
    for (int i = blockIdx.x * 256 + t; i < n4; i += EPARTS * 256) {
        float4 v = ea4[i];
        acc += v.x + v.y + v.z + v.w;
    }
    if (blockIdx.x == 0 && t < (n & 3)) acc += ea[n4 * 4 + t];
    s[t] = acc;
    __syncthreads();
    for (int o = 128; o > 0; o >>= 1) {
        if (t < o) s[t] += s[t + o];
        __syncthreads();
    }
    if (t == 0) part[blockIdx.x] = s[0];
}

// ---- setup: fold weights + finalize easum ----
__global__ void k_setup(const float* __restrict__ W_gat, const float* __restrict__ att_src,
                        const float* __restrict__ att_dst, const float* __restrict__ W_edge,
                        const float* __restrict__ att_edge, const float* __restrict__ b_gat,
                        const float* __restrict__ W_fc1, const float* __restrict__ b_fc1,
                        const float* __restrict__ part, float* __restrict__ consts) {
    __shared__ float s[128];
    int t = threadIdx.x;  // 128 threads
    s[t] = part[t] + part[t + 128];
    __syncthreads();
    for (int o = 64; o > 0; o >>= 1) {
        if (t < o) s[t] += s[t + o];
        __syncthreads();
    }
    if (t == 0) consts[0] = s[0];
    if (t == 0) {
        float c = 0.f;
        for (int k = 0; k < 64; k++) c += W_edge[k] * att_edge[k];
        consts[1] = c;
    }
    if (t < 5) {
        float a = 0.f, b = 0.f;
        for (int c = 0; c < 64; c++) {
            float w = W_gat[t * 64 + c];
            a += w * att_src[c];
            b += w * att_dst[c];
        }
        consts[2 + t] = a;
        consts[7 + t] = b;
    }
    float bcv = b_fc1[t];
    for (int c = 0; c < 64; c++) bcv += b_gat[c] * W_fc1[c * 128 + t];
    consts[16 + t] = bcv;
    for (int k = 0; k < 5; k++) {
        float w = 0.f;
        for (int c = 0; c < 64; c++) w += W_gat[k * 64 + c] * W_fc1[c * 128 + t];
        consts[144 + k * 128 + t] = w;
    }
}

// ---- merged: blocks [0,nbl) per-node prep; blocks [nbl,nbl+ebl) edge binning ----
// node: xh = 8 halves {x0..x4, a_s, 0, 0} (16B); a_s, a_d f32 arrays; fused bstart
__global__ void k_np1(const float* __restrict__ x, const float* __restrict__ consts,
                      uint4* __restrict__ xh, float* __restrict__ a_s, float* __restrict__ a_d,
                      const int* __restrict__ pb, int* __restrict__ bstart,
                      const int* __restrict__ src, const int* __restrict__ dst,
                      const float* __restrict__ ea,
                      uint2* __restrict__ slab, unsigned* __restrict__ gcur,
                      int N, int B, int E, int R, int CAP, int nbl) {
    if ((int)blockIdx.x < nbl) {
        int i = blockIdx.x * blockDim.x + threadIdx.x;
        if (i >= N) return;
        const float* xi = x + (size_t)i * 5;
        float x0 = xi[0], x1 = xi[1], x2 = xi[2], x3 = xi[3], x4 = xi[4];
        float as = x0 * consts[2] + x1 * consts[3] + x2 * consts[4] + x3 * consts[5] + x4 * consts[6];
        float ad = x0 * consts[7] + x1 * consts[8] + x2 * consts[9] + x3 * consts[10] + x4 * consts[11];
        uint4 pkv;
        pkv.x = pk2(x0, x1);
        pkv.y = pk2(x2, x3);
        pkv.z = pk2(x4, as);
        pkv.w = 0;
        xh[i] = pkv;
        a_s[i] = as;
        a_d[i] = ad;
        int cur = pb[i];
        int prev = (i == 0) ? -1 : pb[i - 1];
        for (int b = prev + 1; b <= cur; b++) bstart[b] = i;
        if (i == N - 1)
            for (int b = cur + 1; b <= B; b++) bstart[b] = N;
        return;
    }
    __shared__ unsigned hist[MAXR], lbase[MAXR], gbase[MAXR], scan[256];
    __shared__ uint2 staged[TILE];
    __shared__ unsigned char bof[TILE];
    int t = threadIdx.x;  // 256
    int e0 = ((int)blockIdx.x - nbl) * TILE;
    int n = E - e0; if (n > TILE) n = TILE;
    for (int i = t; i < MAXR; i += 256) hist[i] = 0;
    __syncthreads();
    unsigned key[RPT]; float val[RPT]; unsigned brk[RPT];
    float ce = consts[1];
#pragma unroll
    for (int k = 0; k < RPT; k++) {
        int idx = t + k * 256;
        brk[k] = 0xFFFFFFFFu;
        if (idx < n) {
            int e = e0 + idx;
            int d = dst[e];
            unsigned b = (unsigned)d >> NPBL;
            key[k] = ((unsigned)src[e] << NPBL) | ((unsigned)d & (NPB - 1));
            val[k] = ce * ea[e];
            unsigned r = atomicAdd(&hist[b], 1u);
            brk[k] = (b << 12) | r;
        }
    }
    __syncthreads();
    unsigned v = (t < R) ? hist[t] : 0;
    if (t < R) gbase[t] = atomicAdd(&gcur[t * GCS], v);
    scan[t] = v;
    __syncthreads();
    for (int off = 1; off < 256; off <<= 1) {
        unsigned add = (t >= off) ? scan[t - off] : 0;
        __syncthreads();
        scan[t] += add;
        __syncthreads();
    }
    if (t < R) lbase[t] = scan[t] - v;
    __syncthreads();
#pragma unroll
    for (int k = 0; k < RPT; k++) {
        if (brk[k] != 0xFFFFFFFFu) {
            unsigned b = brk[k] >> 12, r = brk[k] & 4095u;
            unsigned pos = lbase[b] + r;
            staged[pos] = make_uint2(key[k], __float_as_uint(val[k]));
            bof[pos] = (unsigned char)b;
        }
    }
    __syncthreads();
    for (int i = t; i < n; i += 256) {
        unsigned b = bof[i];
        unsigned slot = gbase[b] + (unsigned)i - lbase[b];
        if (slot < (unsigned)CAP) slab[(size_t)b * CAP + slot] = staged[i];
    }
}

// ---- phase 2: per (slice s, bucket r): LDS aggregation; ONE 16B gather/record ----
// acc stride 7 -> all 32 banks; partials layout (SoA): [r][s][6][NPB]
__global__ void k_p2(const uint2* __restrict__ slab, const unsigned* __restrict__ gcur,
                     const uint4* __restrict__ xh, const float* __restrict__ a_d,
                     float* __restrict__ partials, int S, int CAP, int N) {
    __shared__ float acc[NPB * ASTR];   // 14 KB
    __shared__ float adl[NPB];          // 2 KB
    int t = threadIdx.x;  // 256
    int s = blockIdx.x, r = blockIdx.y;
    for (int i = t; i < NPB; i += 256) {
        int node = r * NPB + i;
        adl[i] = (node < N) ? a_d[node] : 0.f;
    }
    for (int i = t; i < NPB * ASTR; i += 256) acc[i] = 0.f;
    __syncthreads();
    unsigned cnt = gcur[r * GCS]; if (cnt > (unsigned)CAP) cnt = CAP;
    unsigned L = (cnt + (unsigned)S - 1) / (unsigned)S;
    unsigned i0 = (unsigned)s * L, i1 = i0 + L; if (i1 > cnt) i1 = cnt;
    const uint2* sl = slab + (size_t)r * CAP;
    for (unsigned i = i0 + t; i < i1; i += 256) {
        uint2 rec = sl[i];
        uint4 v = xh[rec.x >> NPBL];
        float2 x01 = up2(v.x), x23 = up2(v.y), x4a = up2(v.z);
        unsigned dl = rec.x & (NPB - 1);
        float ex = __expf(lrelu(x4a.y + adl[dl] + __uint_as_float(rec.y)));
        float* a = acc + dl * ASTR;
        unsafeAtomicAdd(a + 0, ex * x01.x);
        unsafeAtomicAdd(a + 1, ex * x01.y);
        unsafeAtomicAdd(a + 2, ex * x23.x);
        unsafeAtomicAdd(a + 3, ex * x23.y);
        unsafeAtomicAdd(a + 4, ex * x4a.x);
        unsafeAtomicAdd(a + 5, ex);
    }
    __syncthreads();
    // SoA transpose writeout: out[comp*NPB + dl] = acc[dl*ASTR + comp]
    float* out = partials + (size_t)(r * S + s) * (NPB * 6);
    for (int j = t; j < NPB * 6; j += 256) {
        int comp = j >> NPBL, dl = j & (NPB - 1);
        out[j] = acc[dl * ASTR + comp];
    }
}

// ---- phase 3: merge S partials + self-loop, normalize -> y SoA [5][N] ----
__global__ void k_p3(const float* __restrict__ partials, const float* __restrict__ x,
                     const float* __restrict__ a_s, const float* __restrict__ a_d,
                     const float* __restrict__ consts, float* __restrict__ y,
                     int N, int S, float inv_E) {
    int i = blockIdx.x * blockDim.x + threadIdx.x;
    if (i >= N) return;
    int r = i >> NPBL, dl = i & (NPB - 1);
    float y0 = 0, y1 = 0, y2 = 0, y3 = 0, y4 = 0, ss = 0;
    const float* p = partials + (size_t)r * S * (NPB * 6) + dl;
    for (int s = 0; s < S; s++) {
        const float* q = p + (size_t)s * (NPB * 6);
        y0 += q[0 * NPB]; y1 += q[1 * NPB]; y2 += q[2 * NPB];
        y3 += q[3 * NPB]; y4 += q[4 * NPB]; ss += q[5 * NPB];
    }
    const float* xi = x + (size_t)i * 5;
    float x0 = xi[0], x1 = xi[1], x2 = xi[2], x3 = xi[3], x4 = xi[4];
    float mean_ea = consts[0] * inv_E;
    float aself = lrelu(a_s[i] + a_d[i] + consts[1] * mean_ea);
    float exs = __expf(aself);
    float inv = 1.f / (ss + exs + 1e-16f);
    y[0 * (size_t)N + i] = (y0 + exs * x0) * inv;
    y[1 * (size_t)N + i] = (y1 + exs * x1) * inv;
    y[2 * (size_t)N + i] = (y2 + exs * x2) * inv;
    y[3 * (size_t)N + i] = (y3 + exs * x3) * inv;
    y[4 * (size_t)N + i] = (y4 + exs * x4) * inv;
}

// ---- pool: 4 quarter-blocks per batch, unroll-4, 4 indep chains, direct store ----
__global__ void k_pool(const float* __restrict__ y, const float* __restrict__ consts,
                       const int* __restrict__ bstart, float* __restrict__ g4, int B, int N) {
    int l = threadIdx.x;  // 128 threads
    int b = blockIdx.x >> 2, q = blockIdx.x & 3;
    int st = bstart[b], en = bstart[b + 1];
    int len = en - st;
    int qlen = (len + 3) >> 2;
    int i0 = st + q * qlen;
    int i1 = i0 + qlen;
    if (i0 > en) i0 = en;
    if (i1 > en) i1 = en;
    float w0 = consts[144 + l], w1 = consts[272 + l], w2 = consts[400 + l],
          w3 = consts[528 + l], w4 = consts[656 + l];
    float bc = consts[16 + l];
    const float* y0 = y;
    const float* y1p = y + (size_t)N;
    const float* y2p = y + 2 * (size_t)N;
    const float* y3p = y + 3 * (size_t)N;
    const float* y4p = y + 4 * (size_t)N;
    float a0 = 0.f, a1 = 0.f, a2 = 0.f, a3 = 0.f;
    int i = i0;
    for (; i + 3 < i1; i += 4) {
        float h0 = bc + y0[i] * w0 + y1p[i] * w1 + y2p[i] * w2 + y3p[i] * w3 + y4p[i] * w4;
        float h1 = bc + y0[i+1] * w0 + y1p[i+1] * w1 + y2p[i+1] * w2 + y3p[i+1] * w3 + y4p[i+1] * w4;
        float h2 = bc + y0[i+2] * w0 + y1p[i+2] * w1 + y2p[i+2] * w2 + y3p[i+2] * w3 + y4p[i+2] * w4;
        float h3 = bc + y0[i+3] * w0 + y1p[i+3] * w1 + y2p[i+3] * w2 + y3p[i+3] * w3 + y4p[i+3] * w4;
        a0 += fmaxf(h0, 0.f);
        a1 += fmaxf(h1, 0.f);
        a2 += fmaxf(h2, 0.f);
        a3 += fmaxf(h3, 0.f);
    }
    for (; i < i1; ++i) {
        float h = bc + y0[i] * w0 + y1p[i] * w1 + y2p[i] * w2 + y3p[i] * w3 + y4p[i] * w4;
        a0 += fmaxf(h, 0.f);
    }
    g4[((size_t)q * B + b) * 128 + l] = (a0 + a1) + (a2 + a3);
}

// ---- head MLP: one block per batch row ----
__global__ void k_head(const float* __restrict__ g4, const int* __restrict__ bstart,
                       const float* __restrict__ agent_state, const float* __restrict__ W_fc2,
                       const float* __restrict__ b_fc2, const float* __restrict__ W_v1,
                       const float* __restrict__ b_v1, const float* __restrict__ W_v2,
                       const float* __restrict__ b_v2, const float* __restrict__ W_a1,
                       const float* __restrict__ b_a1, const float* __restrict__ W_a2,
                       const float* __restrict__ b_a2, float* __restrict__ out, int A, int B) {
    __shared__ float z[192];
    __shared__ float v1s[128], a1s[128], red[128];
    __shared__ float advs[8];
    int b = blockIdx.x, t = threadIdx.x;  // 128 threads
    float cnt = (float)(bstart[b + 1] - bstart[b]);
    cnt = cnt < 1.f ? 1.f : cnt;
    z[t] = (g4[(size_t)b * 128 + t] + g4[((size_t)B + b) * 128 + t]
          + g4[(2 * (size_t)B + b) * 128 + t] + g4[(3 * (size_t)B + b) * 128 + t]) / cnt;
    if (t < 64) {
        float a = b_fc2[t];
        const float* as_ = agent_state + b * 34;
        for (int k = 0; k < 34; k++) a += as_[k] * W_fc2[k * 64 + t];
        z[128 + t] = fmaxf(a, 0.f);
    }
    __syncthreads();
    float v = b_v1[t], a = b_a1[t];
#pragma unroll 4
    for (int j = 0; j < 192; j++) {
        float zj = z[j];
        v += zj * W_v1[j * 128 + t];
        a += zj * W_a1[j * 128 + t];
    }
    v1s[t] = fmaxf(v, 0.f);
    a1s[t] = fmaxf(a, 0.f);
    __syncthreads();
    red[t] = v1s[t] * W_v2[t];
    __syncthreads();
    for (int o = 64; o > 0; o >>= 1) {
        if (t < o) red[t] += red[t + o];
        __syncthreads();
    }
    float value = red[0] + b_v2[0];
    if (t < A) {
        float ad = b_a2[t];
        for (int j = 0; j < 128; j++) ad += a1s[j] * W_a2[j * A + t];
        advs[t] = ad;
    }
    __syncthreads();
    if (t == 0) {
        float m = 0.f;
        for (int j = 0; j < A; j++) m += advs[j];
        m *= (1.f / (float)A);
        for (int j = 0; j < A; j++) out[b * A + j] = value + advs[j] - m;
    }
}

extern "C" void kernel_launch(void* const* d_in, const int* in_sizes, int n_in,
                              void* d_out, int out_size, void* d_ws, size_t ws_size,
                              hipStream_t stream) {
    const float* x        = (const float*)d_in[0];
    const int* edge_index = (const int*)d_in[1];
    const float* ea       = (const float*)d_in[2];
    const float* agent    = (const float*)d_in[3];
    const int* pool_batch = (const int*)d_in[4];
    const float* W_gat    = (const float*)d_in[5];
    const float* att_src  = (const float*)d_in[6];
    const float* att_dst  = (const float*)d_in[7];
    const float* W_edge   = (const float*)d_in[8];
    const float* att_edge = (const float*)d_in[9];
    const float* b_gat    = (const float*)d_in[10];
    const float* W_fc1    = (const float*)d_in[11];
    const float* b_fc1    = (const float*)d_in[12];
    const float* W_fc2    = (const float*)d_in[13];
    const float* b_fc2    = (const float*)d_in[14];
    const float* W_v1     = (const float*)d_in[15];
    const float* b_v1     = (const float*)d_in[16];
    const float* W_v2     = (const float*)d_in[17];
    const float* b_v2     = (const float*)d_in[18];
    const float* W_a1     = (const float*)d_in[19];
    const float* b_a1     = (const float*)d_in[20];
    const float* W_a2     = (const float*)d_in[21];
    const float* b_a2     = (const float*)d_in[22];

    const int N = in_sizes[0] / 5;
    const int E = in_sizes[2];
    const int B = in_sizes[3] / 34;
    const int A = out_size / B;
    const float inv_E = 1.0f / (float)E;

    const int* src = edge_index;
    const int* dst = edge_index + E;

    const int R = (N + NPB - 1) / NPB;            // 200 buckets
    int capBase = (E + R - 1) / R;                // ~8192
    const int CAP = capBase + capBase / 16 + 256;

    // ---- ws layout ----
    char* ws = (char*)d_ws;
    size_t off = 0;
    auto take = [&](size_t bytes) {
        size_t o = off;
        off = (off + bytes + 255) & ~(size_t)255;
        return o;
    };
    size_t o_consts = take(4096);                       // zeroed
    size_t o_gcur   = take((size_t)MAXR * GCS * 4);     // zeroed (64B-padded counters)
    size_t zero_bytes = off;
    size_t o_epart  = take((size_t)EPARTS * 4);
    size_t o_xh     = take((size_t)N * 16);
    size_t o_as     = take((size_t)N * 4);
    size_t o_ad     = take((size_t)N * 4);
    size_t o_y      = take((size_t)N * 5 * 4);
    size_t o_bstart = take((size_t)(B + 1) * 4);
    size_t o_g4     = take((size_t)4 * B * 128 * 4);
    size_t o_slab   = take((size_t)R * CAP * 8);
    size_t o_part   = off;
    size_t perS = (size_t)R * NPB * 6 * 4;
    int S = SLICES;
    while (S > 1 && o_part + (size_t)S * perS > ws_size) S--;

    float* consts   = (float*)(ws + o_consts);
    unsigned* gcur  = (unsigned*)(ws + o_gcur);
    float* epart    = (float*)(ws + o_epart);
    uint4* xh       = (uint4*)(ws + o_xh);
    float* a_s      = (float*)(ws + o_as);
    float* a_d      = (float*)(ws + o_ad);
    float* y        = (float*)(ws + o_y);
    int* bstart     = (int*)(ws + o_bstart);
    float* g4       = (float*)(ws + o_g4);
    uint2* slab     = (uint2*)(ws + o_slab);
    float* partials = (float*)(ws + o_part);

    (void)hipMemsetAsync(d_ws, 0, zero_bytes, stream);

    k_easum_part<<<EPARTS, 256, 0, stream>>>(ea, epart, E);
    k_setup<<<1, 128, 0, stream>>>(W_gat, att_src, att_dst, W_edge, att_edge, b_gat,
                                   W_fc1, b_fc1, epart, consts);

    int nbl = (N + 255) / 256;
    int ebl = (E + TILE - 1) / TILE;
    k_np1<<<nbl + ebl, 256, 0, stream>>>(x, consts, xh, a_s, a_d, pool_batch, bstart,
                                         src, dst, ea, slab, gcur, N, B, E, R, CAP, nbl);
    dim3 g2grid(S, R);
    k_p2<<<g2grid, 256, 0, stream>>>(slab, gcur, xh, a_d, partials, S, CAP, N);
    k_p3<<<nbl, 256, 0, stream>>>(partials, x, a_s, a_d, consts, y, N, S, inv_E);
    k_pool<<<4 * B, 128, 0, stream>>>(y, consts, bstart, g4, B, N);
    k_head<<<B, 128, 0, stream>>>(g4, bstart, agent, W_fc2, b_fc2, W_v1, b_v1, W_v2, b_v2,
                                  W_a1, b_a1, W_a2, b_a2, (float*)d_out, A, B);
}